// Round 4
// baseline (212.975 us; speedup 1.0000x reference)
//
#include <hip/hip_runtime.h>

// Problem constants
#define NB 4
#define SEQ 2048
#define CD 64            // head dim == model dim
#define NHEAD 8
#define BHN (NB * NHEAD) // 32
#define ROWS (NB * SEQ)  // 8192
#define HC 512           // H*CD

#define QSCALE 0.18033688011112042f   // 0.125 * log2(e)
#define SHIFT  23.083120654223414f    // 16 * log2(e)

typedef float f32x4 __attribute__((ext_vector_type(4)));
typedef short s16x8 __attribute__((ext_vector_type(8)));
typedef unsigned short u16;

__device__ __forceinline__ u16 f2bf(float x) {
  union { float f; unsigned u; } v; v.f = x;
  unsigned r = v.u + 0x7FFFu + ((v.u >> 16) & 1u);
  return (u16)(r >> 16);
}

__device__ __forceinline__ float fast_exp2(float x) {
#if __has_builtin(__builtin_amdgcn_exp2f)
  return __builtin_amdgcn_exp2f(x);
#else
  return exp2f(x);
#endif
}

__device__ __forceinline__ f32x4 mfma_bf16(s16x8 a, s16x8 b, f32x4 c) {
  return __builtin_amdgcn_mfma_f32_16x16x32_bf16(a, b, c, 0, 0, 0);
}

// ---------------------------------------------------------------------------
// Kernel 0: weight prep. WT[n][k] = bf16(Wqkv[k][n])  (1536 x 64)
//           WpT[c][k] = bf16(Wproj[k][c])             (64 x 512)
// ---------------------------------------------------------------------------
__global__ void __launch_bounds__(256) prep_kernel(
    const float* __restrict__ Wqkv, const float* __restrict__ Wproj,
    u16* __restrict__ WT, u16* __restrict__ WpT) {
  const int idx = blockIdx.x * 256 + threadIdx.x;
  if (idx < 64 * 1536) {
    const int k = idx / 1536, n = idx % 1536;   // coalesced read
    WT[n * CD + k] = f2bf(Wqkv[idx]);
  }
  if (idx < 512 * 64) {
    const int k = idx >> 6, c = idx & 63;
    WpT[c * HC + k] = f2bf(Wproj[idx]);
  }
}

// ---------------------------------------------------------------------------
// Kernel 1: qkv via MFMA.  x [8192x64] f32 (converted inline), WT bf16.
// Writes Q (scaled by QSCALE), K, V all as [B,H,N,64] bf16.
// grid (128 rowblk, 4 colblk), block 256 = 4 waves; wave = 16 rows x 384 cols
// ---------------------------------------------------------------------------
__global__ void __launch_bounds__(256) qkv_kernel(
    const float* __restrict__ x, const u16* __restrict__ WT,
    u16* __restrict__ Q, u16* __restrict__ K, u16* __restrict__ V) {
  const int t = threadIdx.x;
  const int w = t >> 6, lane = t & 63, quad = lane >> 4, c16 = lane & 15;
  const int r0 = blockIdx.x * 64 + w * 16;
  const int c0 = blockIdx.y * 384;

  s16x8 af[2];
#pragma unroll
  for (int kc = 0; kc < 2; ++kc) {
    const float* xp = x + (size_t)(r0 + c16) * CD + kc * 32 + quad * 8;
    float4 x0 = *(const float4*)xp;
    float4 x1 = *(const float4*)(xp + 4);
    union { u16 u[8]; s16x8 v; } tmp;
    tmp.u[0] = f2bf(x0.x); tmp.u[1] = f2bf(x0.y);
    tmp.u[2] = f2bf(x0.z); tmp.u[3] = f2bf(x0.w);
    tmp.u[4] = f2bf(x1.x); tmp.u[5] = f2bf(x1.y);
    tmp.u[6] = f2bf(x1.z); tmp.u[7] = f2bf(x1.w);
    af[kc] = tmp.v;
  }

  f32x4 acc[24];
#pragma unroll
  for (int nb = 0; nb < 24; ++nb) acc[nb] = (f32x4){0.f, 0.f, 0.f, 0.f};

#pragma unroll
  for (int nb = 0; nb < 24; ++nb) {
#pragma unroll
    for (int kc = 0; kc < 2; ++kc) {
      const s16x8 bf_ = *(const s16x8*)(WT + (size_t)(c0 + nb * 16 + c16) * CD +
                                        kc * 32 + quad * 8);
      acc[nb] = mfma_bf16(af[kc], bf_, acc[nb]);
    }
  }

#pragma unroll
  for (int nb = 0; nb < 24; ++nb) {
    const int cb = c0 + nb * 16;           // wave-uniform column base
    const int three = cb >> 9;
    const int h = (cb >> 6) & 7;
    const int ccb = cb & 63;
    u16* dstp = (three == 0) ? Q : ((three == 1) ? K : V);
    const float scl = (three == 0) ? QSCALE : 1.0f;
#pragma unroll
    for (int i = 0; i < 4; ++i) {
      const int r = r0 + quad * 4 + i;
      const int b = r >> 11, nn = r & (SEQ - 1);
      dstp[((size_t)(b * NHEAD + h) * SEQ + nn) * CD + ccb + c16] =
          f2bf(acc[nb][i] * scl);
    }
  }
}

// ---------------------------------------------------------------------------
// Kernel 2: V transpose per head: Vt[bh][c][n] = V[bh][n][c]
// grid (32 n-tiles, 32 bh), block 256; 64x64 tile via LDS
// ---------------------------------------------------------------------------
__global__ void __launch_bounds__(256) vtrans_kernel(
    const u16* __restrict__ V, u16* __restrict__ Vt) {
  __shared__ __align__(16) u16 T[64][72];
  const int t = threadIdx.x;
  const int bh = blockIdx.y;
  const int n0 = blockIdx.x * 64;
  const u16* src = V + (size_t)bh * SEQ * CD;
  const int r = t >> 3, cg = (t & 7) * 8;
  *(int4*)&T[r][cg]      = *(const int4*)(src + (size_t)(n0 + r) * CD + cg);
  *(int4*)&T[r + 32][cg] = *(const int4*)(src + (size_t)(n0 + r + 32) * CD + cg);
  __syncthreads();
  const int c = t >> 3, ng = (t & 7) * 8;
  u16* dst = Vt + (size_t)bh * CD * SEQ;
#pragma unroll
  for (int half = 0; half < 2; ++half) {
    const int cc = c + half * 32;
    union { u16 u[8]; int4 v; } buf;
#pragma unroll
    for (int j = 0; j < 8; ++j) buf.u[j] = T[ng + j][cc];
    *(int4*)(dst + (size_t)cc * SEQ + n0 + ng) = buf.v;
  }
}

// ---------------------------------------------------------------------------
// Kernel 3: flash attention, BARRIER-FREE.
// K/V MFMA fragments loaded directly from global (L1/L2-served), register
// ping-pong pipeline (load tile kt+32 while computing kt). P round-trip
// through wave-private LDS (lgkmcnt only, no s_barrier anywhere).
// Wave = 32 q-rows; block = 4 indep waves = 128 q. grid (16, 32).
// ---------------------------------------------------------------------------
__global__ void __launch_bounds__(256) attn_kernel(
    const u16* __restrict__ Q, const u16* __restrict__ K,
    const u16* __restrict__ Vt, u16* __restrict__ O) {
  __shared__ __align__(16) u16 Ps[4][32 * 44];  // per-wave P, stride 44

  const int t = threadIdx.x;
  const int w = t >> 6, lane = t & 63, quad = lane >> 4, c16 = lane & 15;
  const int bh = blockIdx.y;
  const int q0 = blockIdx.x * 128 + w * 32;

  const u16* Qb = Q + (size_t)bh * SEQ * CD;
  const u16* Kb = K + (size_t)bh * SEQ * CD;
  const u16* Vb = Vt + (size_t)bh * CD * SEQ;

  s16x8 qf[2][2];
#pragma unroll
  for (int qb = 0; qb < 2; ++qb)
#pragma unroll
    for (int cc = 0; cc < 2; ++cc)
      qf[qb][cc] = *(const s16x8*)(Qb + (size_t)(q0 + qb * 16 + c16) * CD +
                                   cc * 32 + quad * 8);

  s16x8 onesf;
  {
    const short one = (c16 == 0) ? (short)0x3F80 : (short)0;
#pragma unroll
    for (int j = 0; j < 8; ++j) onesf[j] = one;
  }

  f32x4 o[2][4], osum[2];
#pragma unroll
  for (int qb = 0; qb < 2; ++qb) {
    osum[qb] = (f32x4){0.f, 0.f, 0.f, 0.f};
#pragma unroll
    for (int cb = 0; cb < 4; ++cb) o[qb][cb] = (f32x4){0.f, 0.f, 0.f, 0.f};
  }

  // Fragment base pointers.
  // K frag (kb,cc) @ tile kt:  Kb + (kt + kb*16 + c16)*CD + cc*32 + quad*8
  // V frag (cb)    @ tile kt:  Vb + (cb*16 + c16)*SEQ + kt + quad*8
  const u16* kfp = Kb + (size_t)c16 * CD + quad * 8;
  const u16* vfp = Vb + (size_t)c16 * SEQ + quad * 8;
  u16* Pw = Ps[w];

  s16x8 ka[2][2], va[4], kb2[2][2], vb2[4];

#define LOAD_TILE(kf_, vf_, kt_)                                               \
  {                                                                            \
    _Pragma("unroll") for (int kb = 0; kb < 2; ++kb)                           \
        _Pragma("unroll") for (int cc = 0; cc < 2; ++cc)                       \
            kf_[kb][cc] = *(const s16x8*)(kfp + (size_t)((kt_) + kb * 16) * CD \
                                          + cc * 32);                          \
    _Pragma("unroll") for (int cb = 0; cb < 4; ++cb)                           \
        vf_[cb] = *(const s16x8*)(vfp + (size_t)(cb * 16) * SEQ + (kt_));      \
  }

#define COMPUTE_TILE(kf_, vf_)                                                 \
  {                                                                            \
    _Pragma("unroll") for (int qb = 0; qb < 2; ++qb) {                         \
      f32x4 s0 = (f32x4){-SHIFT, -SHIFT, -SHIFT, -SHIFT};                      \
      f32x4 s1 = s0;                                                           \
      s0 = mfma_bf16(qf[qb][0], kf_[0][0], s0);                                \
      s0 = mfma_bf16(qf[qb][1], kf_[0][1], s0);                                \
      s1 = mfma_bf16(qf[qb][0], kf_[1][0], s1);                                \
      s1 = mfma_bf16(qf[qb][1], kf_[1][1], s1);                                \
      _Pragma("unroll") for (int i = 0; i < 4; ++i) {                          \
        Pw[(qb * 16 + quad * 4 + i) * 44 + c16] = f2bf(fast_exp2(s0[i]));      \
        Pw[(qb * 16 + quad * 4 + i) * 44 + 16 + c16] = f2bf(fast_exp2(s1[i])); \
      }                                                                        \
    }                                                                          \
    _Pragma("unroll") for (int qb = 0; qb < 2; ++qb) {                         \
      const s16x8 pf = *(const s16x8*)&Pw[(qb * 16 + c16) * 44 + quad * 8];    \
      _Pragma("unroll") for (int cb = 0; cb < 4; ++cb)                         \
          o[qb][cb] = mfma_bf16(pf, vf_[cb], o[qb][cb]);                       \
      osum[qb] = mfma_bf16(pf, onesf, osum[qb]);                               \
    }                                                                          \
  }

  LOAD_TILE(ka, va, 0)
  for (int kt = 0; kt < SEQ; kt += 64) {
    LOAD_TILE(kb2, vb2, kt + 32)
    COMPUTE_TILE(ka, va)
    if (kt + 64 < SEQ) LOAD_TILE(ka, va, kt + 64)
    COMPUTE_TILE(kb2, vb2)
  }
#undef LOAD_TILE
#undef COMPUTE_TILE

  const int b = bh >> 3, h = bh & 7;
#pragma unroll
  for (int qb = 0; qb < 2; ++qb) {
#pragma unroll
    for (int i = 0; i < 4; ++i) {
      const float l = __shfl(osum[qb][i], lane & 48);
      const float inv = 1.0f / l;
      const int q = q0 + qb * 16 + quad * 4 + i;
      u16* dst = O + ((size_t)(b * SEQ + q)) * HC + h * CD;
#pragma unroll
      for (int cb = 0; cb < 4; ++cb)
        dst[cb * 16 + c16] = f2bf(o[qb][cb][i] * inv);
    }
  }
}

// ---------------------------------------------------------------------------
// Kernel 4: proj via MFMA, k-split 4. O bf16 [8192x512] @ WpT bf16 ->
// out f32 [8192x64]. Block 256 = 4 waves, each wave 128 of K; 16 rows/block.
// grid 512 (2 blocks/CU).
// ---------------------------------------------------------------------------
__global__ void __launch_bounds__(256) proj_kernel(
    const u16* __restrict__ O, const u16* __restrict__ WpT,
    const float* __restrict__ bias, float* __restrict__ out) {
  __shared__ __align__(16) float Cred[4][64][20];  // [wave][col][row+pad]
  const int t = threadIdx.x;
  const int w = t >> 6, lane = t & 63, quad = lane >> 4, c16 = lane & 15;
  const int r0 = blockIdx.x * 16;

  f32x4 acc[4];
#pragma unroll
  for (int nb = 0; nb < 4; ++nb) acc[nb] = (f32x4){0.f, 0.f, 0.f, 0.f};

#pragma unroll
  for (int kk = 0; kk < 4; ++kk) {
    const int kc = w * 4 + kk;
    const s16x8 af = *(const s16x8*)(O + (size_t)(r0 + c16) * HC +
                                     kc * 32 + quad * 8);
#pragma unroll
    for (int nb = 0; nb < 4; ++nb) {
      const s16x8 bf_ = *(const s16x8*)(WpT + (size_t)(nb * 16 + c16) * HC +
                                        kc * 32 + quad * 8);
      acc[nb] = mfma_bf16(af, bf_, acc[nb]);
    }
  }

#pragma unroll
  for (int nb = 0; nb < 4; ++nb)
    *(f32x4*)&Cred[w][nb * 16 + c16][quad * 4] = acc[nb];
  __syncthreads();

  const int col = t & 63, rbase = (t >> 6) * 4;
  const float bv = bias[col];
#pragma unroll
  for (int j = 0; j < 4; ++j) {
    const int r = rbase + j;
    const float s = Cred[0][col][r] + Cred[1][col][r] +
                    Cred[2][col][r] + Cred[3][col][r] + bv;
    out[(size_t)(r0 + r) * CD + col] = s;
  }
}

// ---------------------------------------------------------------------------
extern "C" void kernel_launch(void* const* d_in, const int* in_sizes, int n_in,
                              void* d_out, int out_size, void* d_ws, size_t ws_size,
                              hipStream_t stream) {
  (void)in_sizes; (void)n_in; (void)out_size; (void)ws_size;
  const float* x     = (const float*)d_in[0];
  const float* Wqkv  = (const float*)d_in[1];
  const float* Wproj = (const float*)d_in[2];
  const float* bproj = (const float*)d_in[3];
  float* out = (float*)d_out;

  // workspace layout (u16 units):
  u16* WT  = (u16*)d_ws;                      // 1536*64
  u16* WpT = WT + 1536 * CD;                  // 64*512
  u16* Qw  = WpT + CD * HC;                   // 32*2048*64
  u16* Kw  = Qw + (size_t)BHN * SEQ * CD;
  u16* Vw  = Kw + (size_t)BHN * SEQ * CD;     // V, dead after vtrans
  u16* Vtw = Vw + (size_t)BHN * SEQ * CD;
  u16* Ow  = Vw;                              // O bf16 aliases V (same size)

  prep_kernel<<<384, 256, 0, stream>>>(Wqkv, Wproj, WT, WpT);
  qkv_kernel<<<dim3(128, 4), 256, 0, stream>>>(x, WT, Qw, Kw, Vw);
  vtrans_kernel<<<dim3(32, 32), 256, 0, stream>>>(Vw, Vtw);
  attn_kernel<<<dim3(16, 32), 256, 0, stream>>>(Qw, Kw, Vtw, Ow);
  proj_kernel<<<512, 256, 0, stream>>>(Ow, WpT, bproj, out);
}

// Round 5
// 165.029 us; speedup vs baseline: 1.2905x; 1.2905x over previous
//
#include <hip/hip_runtime.h>

// Problem constants
#define NB 4
#define SEQ 2048
#define CD 64            // head dim == model dim
#define NHEAD 8
#define BHN (NB * NHEAD) // 32
#define ROWS (NB * SEQ)  // 8192
#define HC 512           // H*CD

#define QSCALE 0.18033688011112042f   // 0.125 * log2(e)
#define SHIFT  23.083120654223414f    // 16 * log2(e)

typedef float f32x4 __attribute__((ext_vector_type(4)));
typedef short s16x8 __attribute__((ext_vector_type(8)));
typedef unsigned short u16;
typedef unsigned int u32;

__device__ __forceinline__ u16 f2bf(float x) {
  union { float f; unsigned u; } v; v.f = x;
  unsigned r = v.u + 0x7FFFu + ((v.u >> 16) & 1u);
  return (u16)(r >> 16);
}

__device__ __forceinline__ float fast_exp2(float x) {
#if __has_builtin(__builtin_amdgcn_exp2f)
  return __builtin_amdgcn_exp2f(x);
#else
  return exp2f(x);
#endif
}

__device__ __forceinline__ f32x4 mfma_bf16(s16x8 a, s16x8 b, f32x4 c) {
  return __builtin_amdgcn_mfma_f32_16x16x32_bf16(a, b, c, 0, 0, 0);
}

// async global -> LDS DMA, 16B per lane; LDS dest = base + lane*16 (HW rule)
typedef __attribute__((address_space(1))) const u32* gp1;
typedef __attribute__((address_space(3))) u32* lp3;
__device__ __forceinline__ void dma16(const void* g, void* l) {
  __builtin_amdgcn_global_load_lds((gp1)g, (lp3)l, 16, 0, 0);
}

// ---------------------------------------------------------------------------
// Kernel 0: weight prep. WT[n][k] = bf16(Wqkv[k][n])  (1536 x 64)
//           WpT[c][k] = bf16(Wproj[k][c])             (64 x 512)
// ---------------------------------------------------------------------------
__global__ void __launch_bounds__(256) prep_kernel(
    const float* __restrict__ Wqkv, const float* __restrict__ Wproj,
    u16* __restrict__ WT, u16* __restrict__ WpT) {
  const int idx = blockIdx.x * 256 + threadIdx.x;
  if (idx < 64 * 1536) {
    const int k = idx / 1536, n = idx % 1536;   // coalesced read
    WT[n * CD + k] = f2bf(Wqkv[idx]);
  }
  if (idx < 512 * 64) {
    const int k = idx >> 6, c = idx & 63;
    WpT[c * HC + k] = f2bf(Wproj[idx]);
  }
}

// ---------------------------------------------------------------------------
// Kernel 1: qkv via MFMA.  x [8192x64] f32 (converted inline), WT bf16.
// Q (scaled by QSCALE) and K as [B,H,N,64] bf16;
// V written TILED-TRANSPOSED: Vt[bh][n>>5][c][n&31]  (contiguous 4KB tiles).
// grid (128 rowblk, 8 colblk), block 256 = 4 waves; wave = 16 rows x 192 cols
// ---------------------------------------------------------------------------
__global__ void __launch_bounds__(256) qkv_kernel(
    const float* __restrict__ x, const u16* __restrict__ WT,
    u16* __restrict__ Q, u16* __restrict__ K, u16* __restrict__ Vt) {
  const int t = threadIdx.x;
  const int w = t >> 6, lane = t & 63, quad = lane >> 4, c16 = lane & 15;
  const int r0 = blockIdx.x * 64 + w * 16;
  const int c0 = blockIdx.y * 192;

  s16x8 af[2];
#pragma unroll
  for (int kc = 0; kc < 2; ++kc) {
    const float* xp = x + (size_t)(r0 + c16) * CD + kc * 32 + quad * 8;
    float4 x0 = *(const float4*)xp;
    float4 x1 = *(const float4*)(xp + 4);
    union { u16 u[8]; s16x8 v; } tmp;
    tmp.u[0] = f2bf(x0.x); tmp.u[1] = f2bf(x0.y);
    tmp.u[2] = f2bf(x0.z); tmp.u[3] = f2bf(x0.w);
    tmp.u[4] = f2bf(x1.x); tmp.u[5] = f2bf(x1.y);
    tmp.u[6] = f2bf(x1.z); tmp.u[7] = f2bf(x1.w);
    af[kc] = tmp.v;
  }

  f32x4 acc[12];
#pragma unroll
  for (int nb = 0; nb < 12; ++nb) acc[nb] = (f32x4){0.f, 0.f, 0.f, 0.f};

#pragma unroll
  for (int nb = 0; nb < 12; ++nb) {
#pragma unroll
    for (int kc = 0; kc < 2; ++kc) {
      const s16x8 bf_ = *(const s16x8*)(WT + (size_t)(c0 + nb * 16 + c16) * CD +
                                        kc * 32 + quad * 8);
      acc[nb] = mfma_bf16(af[kc], bf_, acc[nb]);
    }
  }

  const int b = r0 >> 11;
  const int nn0 = r0 & (SEQ - 1);
#pragma unroll
  for (int nb = 0; nb < 12; ++nb) {
    const int cb = c0 + nb * 16;           // wave-uniform column base
    const int three = cb >> 9;
    const int h = (cb >> 6) & 7;
    const int ccb = cb & 63;
    const int bhv = b * NHEAD + h;
    if (three == 2) {
      // V: tiled-transposed, pack 4 consecutive keys -> one 8B store
      union { u16 u[4]; uint2 v; } pk;
#pragma unroll
      for (int i = 0; i < 4; ++i) pk.u[i] = f2bf(acc[nb][i]);
      const size_t off = (size_t)bhv * (SEQ * CD) + (size_t)(nn0 >> 5) * 2048 +
                         (size_t)(ccb + c16) * 32 + (r0 & 31) + quad * 4;
      *(uint2*)(Vt + off) = pk.v;
    } else {
      u16* dstp = (three == 0) ? Q : K;
      const float scl = (three == 0) ? QSCALE : 1.0f;
#pragma unroll
      for (int i = 0; i < 4; ++i) {
        const int nn = nn0 + quad * 4 + i;
        dstp[((size_t)bhv * SEQ + nn) * CD + ccb + c16] = f2bf(acc[nb][i] * scl);
      }
    }
  }
}

// ---------------------------------------------------------------------------
// Kernel 2: flash attention, m97-style async-DMA double-buffered K-loop.
// Block = 2 waves (128 thr), wave = 32 q-rows. K-tile = 32 keys.
// Staging: wave0 -> K tile (4x dma16), wave1 -> V tile (4x dma16), into
// UNPADDED LDS with XOR-swizzled lane->global mapping so b128 fragment reads
// are conflict-free. One __syncthreads per tile (drains prev iter's DMA).
// p = exp2(s - SHIFT) (shift folded into MFMA C-init); row-sums via ones-col
// MFMA. Output O bf16 [B,N,H*64]. grid (32, 32).
// ---------------------------------------------------------------------------
__global__ void __launch_bounds__(128) attn_kernel(
    const u16* __restrict__ Q, const u16* __restrict__ K,
    const u16* __restrict__ Vt, u16* __restrict__ O) {
  __shared__ __align__(16) u16 Ks[2][2048];   // [buf][32 keys x 64c swizzled]
  __shared__ __align__(16) u16 Vs[2][2048];   // [buf][64c x 32 keys swizzled]
  __shared__ __align__(16) u16 Ps[2][32 * 36];// per-wave P [q][key], stride 36

  const int t = threadIdx.x;
  const int w = t >> 6, lane = t & 63, quad = lane >> 4, c16 = lane & 15;
  const int bh = blockIdx.y;
  const int q0 = blockIdx.x * 64 + w * 32;

  const u16* Qb = Q + (size_t)bh * SEQ * CD;
  const u16* Kb = K + (size_t)bh * SEQ * CD;
  const u16* Vb = Vt + (size_t)bh * SEQ * CD;  // tiled [n>>5][c][n&31]

  // Q A-fragments (held in registers for whole loop)
  s16x8 qf[2][2];
#pragma unroll
  for (int qb = 0; qb < 2; ++qb)
#pragma unroll
    for (int cc = 0; cc < 2; ++cc)
      qf[qb][cc] = *(const s16x8*)(Qb + (size_t)(q0 + qb * 16 + c16) * CD +
                                   cc * 32 + quad * 8);

  s16x8 onesf;
  {
    const short one = (c16 == 0) ? (short)0x3F80 : (short)0;
#pragma unroll
    for (int j = 0; j < 8; ++j) onesf[j] = one;
  }

  f32x4 o[2][4], osum[2];
#pragma unroll
  for (int qb = 0; qb < 2; ++qb) {
    osum[qb] = (f32x4){0.f, 0.f, 0.f, 0.f};
#pragma unroll
    for (int cb = 0; cb < 4; ++cb) o[qb][cb] = (f32x4){0.f, 0.f, 0.f, 0.f};
  }

  // staging lane constants (XOR source swizzle; see round-5 notes)
  const int krl = lane >> 3;                        // K: row within 8-row group
  const int kcl = (lane & 7) ^ ((lane >> 3) & 7);   // K: col granule
  const int vrl = lane >> 2;                        // V: row within 16-row group
  const int vcl = (lane & 3) ^ ((lane >> 3) & 3);   // V: col granule

  // fragment LDS offsets (constant per thread, swizzle-matched)
  int kOff[2][2], vOff[4];
#pragma unroll
  for (int kb = 0; kb < 2; ++kb)
#pragma unroll
    for (int cc = 0; cc < 2; ++cc)
      kOff[kb][cc] = (kb * 16 + c16) * 64 + (((cc * 4 + quad) ^ (c16 & 7)) * 8);
#pragma unroll
  for (int cb = 0; cb < 4; ++cb)
    vOff[cb] = (cb * 16 + c16) * 32 + ((quad ^ ((c16 >> 1) & 3)) * 8);

  // prologue: stage tile 0 into buffer 0
  if (w == 0) {
#pragma unroll
    for (int d = 0; d < 4; ++d)
      dma16(Kb + (size_t)(d * 8 + krl) * CD + kcl * 8, &Ks[0][d * 512]);
  } else {
#pragma unroll
    for (int d = 0; d < 4; ++d)
      dma16(Vb + (size_t)(d * 16 + vrl) * 32 + vcl * 8, &Vs[0][d * 512]);
  }

  u16* Pw = Ps[w];

  for (int kt = 0; kt < SEQ; kt += 32) {
    const int bs = (kt >> 5) & 1;
    __syncthreads();  // drains own DMAs (vmcnt 0) + joins: buf[bs] ready

    if (kt + 32 < SEQ) {
      const int ns = bs ^ 1;
      if (w == 0) {
        const u16* src = Kb + (size_t)(kt + 32) * CD;
#pragma unroll
        for (int d = 0; d < 4; ++d)
          dma16(src + (size_t)(d * 8 + krl) * CD + kcl * 8, &Ks[ns][d * 512]);
      } else {
        const u16* src = Vb + (size_t)((kt + 32) >> 5) * 2048;
#pragma unroll
        for (int d = 0; d < 4; ++d)
          dma16(src + (size_t)(d * 16 + vrl) * 32 + vcl * 8, &Vs[ns][d * 512]);
      }
    }

    // fragment loads (conflict-free via swizzle), shared across both q-blocks
    s16x8 kf[2][2], vf[4];
#pragma unroll
    for (int kb = 0; kb < 2; ++kb)
#pragma unroll
      for (int cc = 0; cc < 2; ++cc)
        kf[kb][cc] = *(const s16x8*)&Ks[bs][kOff[kb][cc]];
#pragma unroll
    for (int cb = 0; cb < 4; ++cb)
      vf[cb] = *(const s16x8*)&Vs[bs][vOff[cb]];

#pragma unroll
    for (int qb = 0; qb < 2; ++qb) {
      f32x4 s0 = (f32x4){-SHIFT, -SHIFT, -SHIFT, -SHIFT};
      f32x4 s1 = s0;
      s0 = mfma_bf16(qf[qb][0], kf[0][0], s0);
      s0 = mfma_bf16(qf[qb][1], kf[0][1], s0);
      s1 = mfma_bf16(qf[qb][0], kf[1][0], s1);
      s1 = mfma_bf16(qf[qb][1], kf[1][1], s1);
#pragma unroll
      for (int i = 0; i < 4; ++i) {
        Pw[(qb * 16 + quad * 4 + i) * 36 + c16]      = f2bf(fast_exp2(s0[i]));
        Pw[(qb * 16 + quad * 4 + i) * 36 + 16 + c16] = f2bf(fast_exp2(s1[i]));
      }
    }
#pragma unroll
    for (int qb = 0; qb < 2; ++qb) {
      const s16x8 pf = *(const s16x8*)&Pw[(qb * 16 + c16) * 36 + quad * 8];
#pragma unroll
      for (int cb = 0; cb < 4; ++cb)
        o[qb][cb] = mfma_bf16(pf, vf[cb], o[qb][cb]);
      osum[qb] = mfma_bf16(pf, onesf, osum[qb]);
    }
  }

  const int b = bh >> 3, h = bh & 7;
#pragma unroll
  for (int qb = 0; qb < 2; ++qb) {
#pragma unroll
    for (int i = 0; i < 4; ++i) {
      const float l = __shfl(osum[qb][i], lane & 48);
      const float inv = 1.0f / l;
      const int q = q0 + qb * 16 + quad * 4 + i;
      u16* dst = O + ((size_t)(b * SEQ + q)) * HC + h * CD;
#pragma unroll
      for (int cb = 0; cb < 4; ++cb)
        dst[cb * 16 + c16] = f2bf(o[qb][cb][i] * inv);
    }
  }
}

// ---------------------------------------------------------------------------
// Kernel 3: proj via MFMA, k-split 4. O bf16 [8192x512] @ WpT bf16 ->
// out f32 [8192x64]. Block 256 = 4 waves, each wave 128 of K; 16 rows/block.
// grid 512 (2 blocks/CU).
// ---------------------------------------------------------------------------
__global__ void __launch_bounds__(256) proj_kernel(
    const u16* __restrict__ O, const u16* __restrict__ WpT,
    const float* __restrict__ bias, float* __restrict__ out) {
  __shared__ __align__(16) float Cred[4][64][20];  // [wave][col][row+pad]
  const int t = threadIdx.x;
  const int w = t >> 6, lane = t & 63, quad = lane >> 4, c16 = lane & 15;
  const int r0 = blockIdx.x * 16;

  f32x4 acc[4];
#pragma unroll
  for (int nb = 0; nb < 4; ++nb) acc[nb] = (f32x4){0.f, 0.f, 0.f, 0.f};

#pragma unroll
  for (int kk = 0; kk < 4; ++kk) {
    const int kc = w * 4 + kk;
    const s16x8 af = *(const s16x8*)(O + (size_t)(r0 + c16) * HC +
                                     kc * 32 + quad * 8);
#pragma unroll
    for (int nb = 0; nb < 4; ++nb) {
      const s16x8 bf_ = *(const s16x8*)(WpT + (size_t)(nb * 16 + c16) * HC +
                                        kc * 32 + quad * 8);
      acc[nb] = mfma_bf16(af, bf_, acc[nb]);
    }
  }

#pragma unroll
  for (int nb = 0; nb < 4; ++nb)
    *(f32x4*)&Cred[w][nb * 16 + c16][quad * 4] = acc[nb];
  __syncthreads();

  const int col = t & 63, rbase = (t >> 6) * 4;
  const float bv = bias[col];
#pragma unroll
  for (int j = 0; j < 4; ++j) {
    const int r = rbase + j;
    const float s = Cred[0][col][r] + Cred[1][col][r] +
                    Cred[2][col][r] + Cred[3][col][r] + bv;
    out[(size_t)(r0 + r) * CD + col] = s;
  }
}

// ---------------------------------------------------------------------------
extern "C" void kernel_launch(void* const* d_in, const int* in_sizes, int n_in,
                              void* d_out, int out_size, void* d_ws, size_t ws_size,
                              hipStream_t stream) {
  (void)in_sizes; (void)n_in; (void)out_size; (void)ws_size;
  const float* x     = (const float*)d_in[0];
  const float* Wqkv  = (const float*)d_in[1];
  const float* Wproj = (const float*)d_in[2];
  const float* bproj = (const float*)d_in[3];
  float* out = (float*)d_out;

  // workspace layout (u16 units):
  u16* WT  = (u16*)d_ws;                      // 1536*64
  u16* WpT = WT + 1536 * CD;                  // 64*512
  u16* Qw  = WpT + CD * HC;                   // 32*2048*64 each below
  u16* Kw  = Qw + (size_t)BHN * SEQ * CD;
  u16* Vtw = Kw + (size_t)BHN * SEQ * CD;     // tiled-transposed V
  u16* Ow  = Vtw + (size_t)BHN * SEQ * CD;    // O bf16 [B,N,HC]

  prep_kernel<<<384, 256, 0, stream>>>(Wqkv, Wproj, WT, WpT);
  qkv_kernel<<<dim3(128, 8), 256, 0, stream>>>(x, WT, Qw, Kw, Vtw);
  attn_kernel<<<dim3(32, 32), 128, 0, stream>>>(Qw, Kw, Vtw, Ow);
  proj_kernel<<<512, 256, 0, stream>>>(Ow, WpT, bproj, out);
}

// Round 7
// 157.800 us; speedup vs baseline: 1.3497x; 1.0458x over previous
//
#include <hip/hip_runtime.h>

// Problem constants
#define NB 4
#define SEQ 2048
#define CD 64            // head dim == model dim
#define NHEAD 8
#define BHN (NB * NHEAD) // 32
#define ROWS (NB * SEQ)  // 8192
#define HC 512           // H*CD

#define QSCALE 0.18033688011112042f   // 0.125 * log2(e)
#define SHIFT  23.083120654223414f    // 16 * log2(e)

typedef float f32x4 __attribute__((ext_vector_type(4)));
typedef short s16x8 __attribute__((ext_vector_type(8)));
typedef unsigned short u16;
typedef unsigned int u32;

__device__ __forceinline__ u16 f2bf(float x) {
  union { float f; unsigned u; } v; v.f = x;
  unsigned r = v.u + 0x7FFFu + ((v.u >> 16) & 1u);
  return (u16)(r >> 16);
}

__device__ __forceinline__ float fast_exp2(float x) {
#if __has_builtin(__builtin_amdgcn_exp2f)
  return __builtin_amdgcn_exp2f(x);
#else
  return exp2f(x);
#endif
}

__device__ __forceinline__ f32x4 mfma_bf16(s16x8 a, s16x8 b, f32x4 c) {
  return __builtin_amdgcn_mfma_f32_16x16x32_bf16(a, b, c, 0, 0, 0);
}

// async global -> LDS DMA, 16B per lane; LDS dest = uniform base + lane*16
typedef __attribute__((address_space(1))) const u32* gp1;
typedef __attribute__((address_space(3))) u32* lp3;
__device__ __forceinline__ void dma16(const void* g, void* l) {
  __builtin_amdgcn_global_load_lds((gp1)g, (lp3)l, 16, 0, 0);
}

// ---------------------------------------------------------------------------
// Kernel 0: weight prep. WT[n][k] = bf16(Wqkv[k][n])  (1536 x 64)
//           WpT[c][k] = bf16(Wproj[k][c])             (64 x 512)
// ---------------------------------------------------------------------------
__global__ void __launch_bounds__(256) prep_kernel(
    const float* __restrict__ Wqkv, const float* __restrict__ Wproj,
    u16* __restrict__ WT, u16* __restrict__ WpT) {
  const int idx = blockIdx.x * 256 + threadIdx.x;
  if (idx < 64 * 1536) {
    const int k = idx / 1536, n = idx % 1536;   // coalesced read
    WT[n * CD + k] = f2bf(Wqkv[idx]);
  }
  if (idx < 512 * 64) {
    const int k = idx >> 6, c = idx & 63;
    WpT[c * HC + k] = f2bf(Wproj[idx]);
  }
}

// ---------------------------------------------------------------------------
// Kernel 1: qkv via MFMA, LDS-staged (x-tile + WT-tile coalesced into LDS;
// no divergent global fragment loads). Q (scaled) & K as [B,H,N,64] bf16;
// V tiled-transposed: Vt[bh][n>>5][c][n&31].
// grid (128 rowblk, 8 colblk), block 256 = 4 waves; wave = 16 rows x 192 cols
// ---------------------------------------------------------------------------
__global__ void __launch_bounds__(256) qkv_kernel(
    const float* __restrict__ x, const u16* __restrict__ WT,
    u16* __restrict__ Q, u16* __restrict__ K, u16* __restrict__ Vt) {
  __shared__ __align__(16) u16 xs[64 * 72];    // [row][c] stride 72 (16B-mult)
  __shared__ __align__(16) u16 wts[192 * 72];  // [n][k]  stride 72

  const int t = threadIdx.x;
  const int w = t >> 6, lane = t & 63, quad = lane >> 4, c16 = lane & 15;
  const int rb = blockIdx.x * 64;
  const int c0 = blockIdx.y * 192;

  // stage x tile (64 rows x 64 c), f32 -> bf16, coalesced
  {
    const int row = t >> 2, cc0 = (t & 3) * 16;
    const float* xp = x + (size_t)(rb + row) * CD + cc0;
    union { u16 u[16]; int4 v[2]; } bx;
#pragma unroll
    for (int j = 0; j < 16; j += 4) {
      float4 xv = *(const float4*)(xp + j);
      bx.u[j] = f2bf(xv.x); bx.u[j + 1] = f2bf(xv.y);
      bx.u[j + 2] = f2bf(xv.z); bx.u[j + 3] = f2bf(xv.w);
    }
    *(int4*)&xs[row * 72 + cc0] = bx.v[0];
    *(int4*)&xs[row * 72 + cc0 + 8] = bx.v[1];
  }
  // stage WT tile (192 rows x 64 k), coalesced
#pragma unroll
  for (int pass = 0; pass < 3; ++pass) {
    const int row = pass * 64 + (t >> 2), cc0 = (t & 3) * 16;
    const u16* src = WT + (size_t)(c0 + row) * CD + cc0;
    *(int4*)&wts[row * 72 + cc0] = *(const int4*)src;
    *(int4*)&wts[row * 72 + cc0 + 8] = *(const int4*)(src + 8);
  }
  __syncthreads();

  s16x8 af[2];
#pragma unroll
  for (int kc = 0; kc < 2; ++kc)
    af[kc] = *(const s16x8*)&xs[(w * 16 + c16) * 72 + kc * 32 + quad * 8];

  f32x4 acc[12];
#pragma unroll
  for (int nb = 0; nb < 12; ++nb) acc[nb] = (f32x4){0.f, 0.f, 0.f, 0.f};

#pragma unroll
  for (int nb = 0; nb < 12; ++nb) {
#pragma unroll
    for (int kc = 0; kc < 2; ++kc) {
      const s16x8 bf_ =
          *(const s16x8*)&wts[(nb * 16 + c16) * 72 + kc * 32 + quad * 8];
      acc[nb] = mfma_bf16(af[kc], bf_, acc[nb]);
    }
  }

  const int rw = rb + w * 16;
  const int b = rw >> 11;
  const int nn0 = rw & (SEQ - 1);
#pragma unroll
  for (int nb = 0; nb < 12; ++nb) {
    const int cb = c0 + nb * 16;
    const int three = cb >> 9;
    const int h = (cb >> 6) & 7;
    const int ccb = cb & 63;
    const int bhv = b * NHEAD + h;
    if (three == 2) {
      union { u16 u[4]; uint2 v; } pk;
#pragma unroll
      for (int i = 0; i < 4; ++i) pk.u[i] = f2bf(acc[nb][i]);
      const size_t off = (size_t)bhv * (SEQ * CD) + (size_t)(nn0 >> 5) * 2048 +
                         (size_t)(ccb + c16) * 32 + (rw & 31) + quad * 4;
      *(uint2*)(Vt + off) = pk.v;
    } else {
      u16* dstp = (three == 0) ? Q : K;
      const float scl = (three == 0) ? QSCALE : 1.0f;
#pragma unroll
      for (int i = 0; i < 4; ++i) {
        const int nn = nn0 + quad * 4 + i;
        dstp[((size_t)bhv * SEQ + nn) * CD + ccb + c16] = f2bf(acc[nb][i] * scl);
      }
    }
  }
}

// ---------------------------------------------------------------------------
// Kernel 2: flash attention, SINGLE-WAVE blocks (64 thr), 64 q-rows/wave.
// S^T = K . Q^T formulation: C-layout gives each lane 4 consecutive keys per
// q -> P packed b64 writes into Ps[q][key] (stride 40), read back as
// contiguous b128 A-frags for PV. DMA double-buffered K/V tiles (R5-verified
// XOR swizzle, 0 conflicts). The per-tile __syncthreads is wave-private:
// vmcnt drain stalls only this block; ~7 blocks/CU (LDS 20.9KB) overlap.
// p = exp2(s - SHIFT) folded into MFMA C-init; row-sums via ones-col MFMA.
// Output O bf16 [B,N,H*64]. grid (32, 32).
// ---------------------------------------------------------------------------
__global__ void __launch_bounds__(64) attn_kernel(
    const u16* __restrict__ Q, const u16* __restrict__ K,
    const u16* __restrict__ Vt, u16* __restrict__ O) {
  __shared__ __align__(16) u16 Ks[2][2048];   // [buf][32k x 64c swizzled]
  __shared__ __align__(16) u16 Vs[2][2048];   // [buf][64c x 32k swizzled]
  __shared__ __align__(16) u16 Ps[64 * 40];   // P [q][key] stride 40

  const int lane = threadIdx.x;
  const int quad = lane >> 4, c16 = lane & 15;
  const int bh = blockIdx.y;
  const int q0 = blockIdx.x * 64;

  const u16* Qb = Q + (size_t)bh * SEQ * CD;
  const u16* Kb = K + (size_t)bh * SEQ * CD;
  const u16* Vb = Vt + (size_t)bh * SEQ * CD;  // tiled [n>>5][c][n&31]

  // Q B-operand fragments: B[k=c][n=q], lane n=c16 -> q, k=quad*8+j -> c
  s16x8 qfb[4][2];
#pragma unroll
  for (int qb = 0; qb < 4; ++qb)
#pragma unroll
    for (int cc = 0; cc < 2; ++cc)
      qfb[qb][cc] = *(const s16x8*)(Qb + (size_t)(q0 + qb * 16 + c16) * CD +
                                    cc * 32 + quad * 8);

  s16x8 onesf;
  {
    const short one = (c16 == 0) ? (short)0x3F80 : (short)0;
#pragma unroll
    for (int j = 0; j < 8; ++j) onesf[j] = one;
  }

  f32x4 o[4][4], osum[4];
#pragma unroll
  for (int qb = 0; qb < 4; ++qb) {
    osum[qb] = (f32x4){0.f, 0.f, 0.f, 0.f};
#pragma unroll
    for (int cb = 0; cb < 4; ++cb) o[qb][cb] = (f32x4){0.f, 0.f, 0.f, 0.f};
  }

  // staging lane constants (R5-verified XOR swizzle, 0 conflicts)
  const int krl = lane >> 3, kcl = (lane & 7) ^ ((lane >> 3) & 7);
  const int vrl = lane >> 2, vcl = (lane & 3) ^ ((lane >> 3) & 3);

  // fragment LDS offsets (swizzle-matched)
  int kOff[2][2], vOff[4];
#pragma unroll
  for (int kb = 0; kb < 2; ++kb)
#pragma unroll
    for (int cc = 0; cc < 2; ++cc)
      kOff[kb][cc] = (kb * 16 + c16) * 64 + (((cc * 4 + quad) ^ (c16 & 7)) * 8);
#pragma unroll
  for (int cb = 0; cb < 4; ++cb)
    vOff[cb] = (cb * 16 + c16) * 32 + ((quad ^ ((c16 >> 1) & 3)) * 8);

#define STAGE_TILE(buf_, kt_)                                                  \
  {                                                                            \
    const u16* ksrc = Kb + (size_t)(kt_) * CD;                                 \
    _Pragma("unroll") for (int d = 0; d < 4; ++d)                              \
        dma16(ksrc + (size_t)(d * 8 + krl) * CD + kcl * 8,                     \
              &Ks[buf_][d * 512]);                                             \
    const u16* vsrc = Vb + (size_t)((kt_) >> 5) * 2048;                        \
    _Pragma("unroll") for (int d = 0; d < 4; ++d)                              \
        dma16(vsrc + (size_t)(d * 16 + vrl) * 32 + vcl * 8,                    \
              &Vs[buf_][d * 512]);                                             \
  }

  STAGE_TILE(0, 0)

  for (int it = 0; it < SEQ / 32; ++it) {
    const int bs = it & 1;
    __syncthreads();  // wave-private: drains own DMA (had full tile to fly)

    if (it + 1 < SEQ / 32) STAGE_TILE(bs ^ 1, (it + 1) * 32)

    s16x8 kf[2][2], vf[4];
#pragma unroll
    for (int kb = 0; kb < 2; ++kb)
#pragma unroll
      for (int cc = 0; cc < 2; ++cc)
        kf[kb][cc] = *(const s16x8*)&Ks[bs][kOff[kb][cc]];
#pragma unroll
    for (int cb = 0; cb < 4; ++cb)
      vf[cb] = *(const s16x8*)&Vs[bs][vOff[cb]];

    // S^T = K.Q^T : D[key][q]; lane holds q=c16, keys kb*16+quad*4+i
#pragma unroll
    for (int qb = 0; qb < 4; ++qb) {
#pragma unroll
      for (int kb = 0; kb < 2; ++kb) {
        f32x4 s = (f32x4){-SHIFT, -SHIFT, -SHIFT, -SHIFT};
        s = mfma_bf16(kf[kb][0], qfb[qb][0], s);
        s = mfma_bf16(kf[kb][1], qfb[qb][1], s);
        const u16 p0 = f2bf(fast_exp2(s[0]));
        const u16 p1 = f2bf(fast_exp2(s[1]));
        const u16 p2 = f2bf(fast_exp2(s[2]));
        const u16 p3 = f2bf(fast_exp2(s[3]));
        uint2 pk;
        pk.x = (u32)p0 | ((u32)p1 << 16);
        pk.y = (u32)p2 | ((u32)p3 << 16);
        *(uint2*)&Ps[(qb * 16 + c16) * 40 + kb * 16 + quad * 4] = pk;
      }
    }
    // PV: A = P[q][key] (contiguous b128), B = V^T[c][key]
#pragma unroll
    for (int qb = 0; qb < 4; ++qb) {
      const s16x8 pf = *(const s16x8*)&Ps[(qb * 16 + c16) * 40 + quad * 8];
#pragma unroll
      for (int cb = 0; cb < 4; ++cb)
        o[qb][cb] = mfma_bf16(pf, vf[cb], o[qb][cb]);
      osum[qb] = mfma_bf16(pf, onesf, osum[qb]);
    }
  }
#undef STAGE_TILE

  const int b = bh >> 3, h = bh & 7;
#pragma unroll
  for (int qb = 0; qb < 4; ++qb) {
#pragma unroll
    for (int i = 0; i < 4; ++i) {
      const float l = __shfl(osum[qb][i], lane & 48);
      const float inv = 1.0f / l;
      const int q = q0 + qb * 16 + quad * 4 + i;
      u16* dst = O + ((size_t)(b * SEQ + q)) * HC + h * CD;
#pragma unroll
      for (int cb = 0; cb < 4; ++cb)
        dst[cb * 16 + c16] = f2bf(o[qb][cb][i] * inv);
    }
  }
}

// ---------------------------------------------------------------------------
// Kernel 3: proj via MFMA. O bf16 [8192x512] @ WpT bf16 -> out f32 [8192x64].
// Wp B-frags preloaded to registers (fly during staging); O tile staged
// coalesced into LDS. Block 256 = 4 waves, k-split 4 + LDS f32 reduce.
// grid 512 (16 rows/block).
// ---------------------------------------------------------------------------
__global__ void __launch_bounds__(256) proj_kernel(
    const u16* __restrict__ O, const u16* __restrict__ WpT,
    const float* __restrict__ bias, float* __restrict__ out) {
  __shared__ __align__(16) u16 Ls[16 * 520];       // [row][k] stride 520
  __shared__ __align__(16) float Cred[4][64][20];  // [wave][col][row+pad]
  const int t = threadIdx.x;
  const int w = t >> 6, lane = t & 63, quad = lane >> 4, c16 = lane & 15;
  const int r0 = blockIdx.x * 16;

  // preload Wp B-frags to registers
  s16x8 wf[4][4];
#pragma unroll
  for (int kc = 0; kc < 4; ++kc)
#pragma unroll
    for (int nb = 0; nb < 4; ++nb)
      wf[kc][nb] = *(const s16x8*)(WpT + (size_t)(nb * 16 + c16) * HC +
                                   w * 128 + kc * 32 + quad * 8);

  // stage O tile coalesced: 16 lanes cover 256B of a row, 16 rows, 4 passes
  {
    const int row = t >> 4, cg = (t & 15) * 8;
#pragma unroll
    for (int p = 0; p < 4; ++p)
      *(int4*)&Ls[row * 520 + p * 128 + cg] =
          *(const int4*)(O + (size_t)(r0 + row) * HC + p * 128 + cg);
  }
  __syncthreads();

  f32x4 acc[4];
#pragma unroll
  for (int nb = 0; nb < 4; ++nb) acc[nb] = (f32x4){0.f, 0.f, 0.f, 0.f};
#pragma unroll
  for (int kc = 0; kc < 4; ++kc) {
    const s16x8 af =
        *(const s16x8*)&Ls[c16 * 520 + w * 128 + kc * 32 + quad * 8];
#pragma unroll
    for (int nb = 0; nb < 4; ++nb)
      acc[nb] = mfma_bf16(af, wf[kc][nb], acc[nb]);
  }

#pragma unroll
  for (int nb = 0; nb < 4; ++nb)
    *(f32x4*)&Cred[w][nb * 16 + c16][quad * 4] = acc[nb];
  __syncthreads();

  const int col = t & 63, rbase = (t >> 6) * 4;
  const float bv = bias[col];
#pragma unroll
  for (int j = 0; j < 4; ++j) {
    const int r = rbase + j;
    out[(size_t)(r0 + r) * CD + col] = Cred[0][col][r] + Cred[1][col][r] +
                                       Cred[2][col][r] + Cred[3][col][r] + bv;
  }
}

// ---------------------------------------------------------------------------
extern "C" void kernel_launch(void* const* d_in, const int* in_sizes, int n_in,
                              void* d_out, int out_size, void* d_ws, size_t ws_size,
                              hipStream_t stream) {
  (void)in_sizes; (void)n_in; (void)out_size; (void)ws_size;
  const float* x     = (const float*)d_in[0];
  const float* Wqkv  = (const float*)d_in[1];
  const float* Wproj = (const float*)d_in[2];
  const float* bproj = (const float*)d_in[3];
  float* out = (float*)d_out;

  // workspace layout (u16 units), 33.8 MB total (R5-proven size)
  u16* WT  = (u16*)d_ws;                      // 1536*64
  u16* WpT = WT + 1536 * CD;                  // 64*512
  u16* Qw  = WpT + CD * HC;                   // 8 MB each below
  u16* Kw  = Qw + (size_t)BHN * SEQ * CD;
  u16* Vtw = Kw + (size_t)BHN * SEQ * CD;     // tiled-transposed V
  u16* Ow  = Vtw + (size_t)BHN * SEQ * CD;    // O bf16 [B,N,HC]

  prep_kernel<<<384, 256, 0, stream>>>(Wqkv, Wproj, WT, WpT);
  qkv_kernel<<<dim3(128, 8), 256, 0, stream>>>(x, WT, Qw, Kw, Vtw);
  attn_kernel<<<dim3(32, 32), 64, 0, stream>>>(Qw, Kw, Vtw, Ow);
  proj_kernel<<<512, 256, 0, stream>>>(Ow, WpT, bproj, out);
}

// Round 8
// 126.050 us; speedup vs baseline: 1.6896x; 1.2519x over previous
//
#include <hip/hip_runtime.h>

// Problem constants
#define NB 4
#define SEQ 2048
#define CD 64            // head dim == model dim
#define NHEAD 8
#define BHN (NB * NHEAD) // 32
#define ROWS (NB * SEQ)  // 8192
#define HC 512           // H*CD

#define QSCALE 0.18033688011112042f   // 0.125 * log2(e)
#define SHIFT  23.083120654223414f    // 16 * log2(e)

typedef float f32x4 __attribute__((ext_vector_type(4)));
typedef short s16x8 __attribute__((ext_vector_type(8)));
typedef unsigned short u16;
typedef unsigned int u32;

__device__ __forceinline__ u16 f2bf(float x) {
  union { float f; unsigned u; } v; v.f = x;
  unsigned r = v.u + 0x7FFFu + ((v.u >> 16) & 1u);
  return (u16)(r >> 16);
}

__device__ __forceinline__ float fast_exp2(float x) {
#if __has_builtin(__builtin_amdgcn_exp2f)
  return __builtin_amdgcn_exp2f(x);
#else
  return exp2f(x);
#endif
}

__device__ __forceinline__ u32 bitsf(float x) {
  union { float f; u32 u; } v; v.f = x; return v.u;
}

// pack hi16 of two f32 (truncating bf16 convert): {lo:=a_hi16, hi:=b_hi16}
__device__ __forceinline__ u32 pack_trunc(float a, float b) {
#if __has_builtin(__builtin_amdgcn_perm)
  return __builtin_amdgcn_perm(bitsf(b), bitsf(a), 0x07060302u);
#else
  return (bitsf(a) >> 16) | (bitsf(b) & 0xFFFF0000u);
#endif
}

__device__ __forceinline__ f32x4 mfma_bf16(s16x8 a, s16x8 b, f32x4 c) {
  return __builtin_amdgcn_mfma_f32_16x16x32_bf16(a, b, c, 0, 0, 0);
}

// async global -> LDS DMA, 16B per lane; LDS dest = uniform base + lane*16
typedef __attribute__((address_space(1))) const u32* gp1;
typedef __attribute__((address_space(3))) u32* lp3;
__device__ __forceinline__ void dma16(const void* g, void* l) {
  __builtin_amdgcn_global_load_lds((gp1)g, (lp3)l, 16, 0, 0);
}

// ---------------------------------------------------------------------------
// Kernel 0: weight prep. WT[n][k] = bf16(Wqkv[k][n])  (1536 x 64)
//           WpT[c][k] = bf16(Wproj[k][c])             (64 x 512)
// ---------------------------------------------------------------------------
__global__ void __launch_bounds__(256) prep_kernel(
    const float* __restrict__ Wqkv, const float* __restrict__ Wproj,
    u16* __restrict__ WT, u16* __restrict__ WpT) {
  const int idx = blockIdx.x * 256 + threadIdx.x;
  if (idx < 64 * 1536) {
    const int k = idx / 1536, n = idx % 1536;   // coalesced read
    WT[n * CD + k] = f2bf(Wqkv[idx]);
  }
  if (idx < 512 * 64) {
    const int k = idx >> 6, c = idx & 63;
    WpT[c * HC + k] = f2bf(Wproj[idx]);
  }
}

// ---------------------------------------------------------------------------
// Kernel 1: qkv via MFMA, LDS-staged. Q (scaled) & K as [B,H,N,64] bf16;
// V tiled-transposed: Vt[bh][n>>5][c][n&31].
// grid (128 rowblk, 8 colblk), block 256 = 4 waves; wave = 16 rows x 192 cols
// ---------------------------------------------------------------------------
__global__ void __launch_bounds__(256) qkv_kernel(
    const float* __restrict__ x, const u16* __restrict__ WT,
    u16* __restrict__ Q, u16* __restrict__ K, u16* __restrict__ Vt) {
  __shared__ __align__(16) u16 xs[64 * 72];    // [row][c] stride 72 (16B-mult)
  __shared__ __align__(16) u16 wts[192 * 72];  // [n][k]  stride 72

  const int t = threadIdx.x;
  const int w = t >> 6, lane = t & 63, quad = lane >> 4, c16 = lane & 15;
  const int rb = blockIdx.x * 64;
  const int c0 = blockIdx.y * 192;

  // stage x tile (64 rows x 64 c), f32 -> bf16, coalesced
  {
    const int row = t >> 2, cc0 = (t & 3) * 16;
    const float* xp = x + (size_t)(rb + row) * CD + cc0;
    union { u16 u[16]; int4 v[2]; } bx;
#pragma unroll
    for (int j = 0; j < 16; j += 4) {
      float4 xv = *(const float4*)(xp + j);
      bx.u[j] = f2bf(xv.x); bx.u[j + 1] = f2bf(xv.y);
      bx.u[j + 2] = f2bf(xv.z); bx.u[j + 3] = f2bf(xv.w);
    }
    *(int4*)&xs[row * 72 + cc0] = bx.v[0];
    *(int4*)&xs[row * 72 + cc0 + 8] = bx.v[1];
  }
  // stage WT tile (192 rows x 64 k), coalesced
#pragma unroll
  for (int pass = 0; pass < 3; ++pass) {
    const int row = pass * 64 + (t >> 2), cc0 = (t & 3) * 16;
    const u16* src = WT + (size_t)(c0 + row) * CD + cc0;
    *(int4*)&wts[row * 72 + cc0] = *(const int4*)src;
    *(int4*)&wts[row * 72 + cc0 + 8] = *(const int4*)(src + 8);
  }
  __syncthreads();

  s16x8 af[2];
#pragma unroll
  for (int kc = 0; kc < 2; ++kc)
    af[kc] = *(const s16x8*)&xs[(w * 16 + c16) * 72 + kc * 32 + quad * 8];

  f32x4 acc[12];
#pragma unroll
  for (int nb = 0; nb < 12; ++nb) acc[nb] = (f32x4){0.f, 0.f, 0.f, 0.f};

#pragma unroll
  for (int nb = 0; nb < 12; ++nb) {
#pragma unroll
    for (int kc = 0; kc < 2; ++kc) {
      const s16x8 bf_ =
          *(const s16x8*)&wts[(nb * 16 + c16) * 72 + kc * 32 + quad * 8];
      acc[nb] = mfma_bf16(af[kc], bf_, acc[nb]);
    }
  }

  const int rw = rb + w * 16;
  const int b = rw >> 11;
  const int nn0 = rw & (SEQ - 1);
#pragma unroll
  for (int nb = 0; nb < 12; ++nb) {
    const int cb = c0 + nb * 16;
    const int three = cb >> 9;
    const int h = (cb >> 6) & 7;
    const int ccb = cb & 63;
    const int bhv = b * NHEAD + h;
    if (three == 2) {
      union { u16 u[4]; uint2 v; } pk;
#pragma unroll
      for (int i = 0; i < 4; ++i) pk.u[i] = f2bf(acc[nb][i]);
      const size_t off = (size_t)bhv * (SEQ * CD) + (size_t)(nn0 >> 5) * 2048 +
                         (size_t)(ccb + c16) * 32 + (rw & 31) + quad * 4;
      *(uint2*)(Vt + off) = pk.v;
    } else {
      u16* dstp = (three == 0) ? Q : K;
      const float scl = (three == 0) ? QSCALE : 1.0f;
#pragma unroll
      for (int i = 0; i < 4; ++i) {
        const int nn = nn0 + quad * 4 + i;
        dstp[((size_t)bhv * SEQ + nn) * CD + ccb + c16] = f2bf(acc[nb][i] * scl);
      }
    }
  }
}

// ---------------------------------------------------------------------------
// Kernel 2: flash attention, IN-BLOCK K-SPLIT x2.
// Block = 2 waves (128 thr). Both waves compute the SAME 64 q-rows; wave w
// handles keys [w*1024, (w+1)*1024), each with its own DMA-double-buffered
// K/V staging (R5-verified XOR swizzle, 0 conflicts). Fixed-shift softmax
// (p = exp2(s-SHIFT), shift in MFMA C-init) makes the K-split combine exact:
// out = (o0+o1)/(l0+l1). Wave1 publishes its unnormalized f32 partial via its
// own dead staging LDS; one barrier; wave0 combines + writes O bf16.
// S^T = K.Q^T formulation; per-qb interleaved P (16x40) round-trip; P packed
// with truncating v_perm. grid (32, 32), 2048 waves = 8 waves/CU.
// ---------------------------------------------------------------------------
__global__ void __launch_bounds__(128, 2) attn_kernel(
    const u16* __restrict__ Q, const u16* __restrict__ K,
    const u16* __restrict__ Vt, u16* __restrict__ O) {
  // layout (u16): [w*8192 .. ]: K buf0|K buf1|V buf0|V buf1 (2048 each)
  //               [16384 + w*640]: per-wave P (16 rows x stride 40)
  __shared__ __align__(16) u16 smem[17664];

  const int t = threadIdx.x;
  const int w = t >> 6, lane = t & 63, quad = lane >> 4, c16 = lane & 15;
  const int bh = blockIdx.y;
  const int q0 = blockIdx.x * 64;
  const int kt0 = w * (SEQ / 2);

  u16* KsW = smem + w * 8192;          // [buf][2048]
  u16* VsW = smem + w * 8192 + 4096;   // [buf][2048]
  u16* Pw  = smem + 16384 + w * 640;   // [16*40]

  const u16* Qb = Q + (size_t)bh * SEQ * CD;
  const u16* Kb = K + (size_t)bh * SEQ * CD;
  const u16* Vb = Vt + (size_t)bh * SEQ * CD;  // tiled [n>>5][c][n&31]

  // Q B-operand fragments (same for both waves): B[k=c][n=q]
  s16x8 qfb[4][2];
#pragma unroll
  for (int qb = 0; qb < 4; ++qb)
#pragma unroll
    for (int cc = 0; cc < 2; ++cc)
      qfb[qb][cc] = *(const s16x8*)(Qb + (size_t)(q0 + qb * 16 + c16) * CD +
                                    cc * 32 + quad * 8);

  s16x8 onesf;
  {
    const short one = (c16 == 0) ? (short)0x3F80 : (short)0;
#pragma unroll
    for (int j = 0; j < 8; ++j) onesf[j] = one;
  }

  f32x4 o[4][4], osum[4];
#pragma unroll
  for (int qb = 0; qb < 4; ++qb) {
    osum[qb] = (f32x4){0.f, 0.f, 0.f, 0.f};
#pragma unroll
    for (int cb = 0; cb < 4; ++cb) o[qb][cb] = (f32x4){0.f, 0.f, 0.f, 0.f};
  }

  // staging lane constants (R5-verified XOR swizzle, 0 conflicts)
  const int krl = lane >> 3, kcl = (lane & 7) ^ ((lane >> 3) & 7);
  const int vrl = lane >> 2, vcl = (lane & 3) ^ ((lane >> 3) & 3);

  // fragment LDS offsets (swizzle-matched), relative to tile start
  int kOff[2][2], vOff[4];
#pragma unroll
  for (int kb = 0; kb < 2; ++kb)
#pragma unroll
    for (int cc = 0; cc < 2; ++cc)
      kOff[kb][cc] = (kb * 16 + c16) * 64 + (((cc * 4 + quad) ^ (c16 & 7)) * 8);
#pragma unroll
  for (int cb = 0; cb < 4; ++cb)
    vOff[cb] = (cb * 16 + c16) * 32 + ((quad ^ ((c16 >> 1) & 3)) * 8);

#define STAGE_TILE(buf_, kt_)                                                  \
  {                                                                            \
    const u16* ksrc = Kb + (size_t)(kt_) * CD;                                 \
    _Pragma("unroll") for (int d = 0; d < 4; ++d)                              \
        dma16(ksrc + (size_t)(d * 8 + krl) * CD + kcl * 8,                     \
              KsW + (buf_) * 2048 + d * 512);                                  \
    const u16* vsrc = Vb + (size_t)((kt_) >> 5) * 2048;                        \
    _Pragma("unroll") for (int d = 0; d < 4; ++d)                              \
        dma16(vsrc + (size_t)(d * 16 + vrl) * 32 + vcl * 8,                    \
              VsW + (buf_) * 2048 + d * 512);                                  \
  }

  STAGE_TILE(0, kt0)

  for (int it = 0; it < 32; ++it) {
    const int bs = it & 1;
    __syncthreads();  // both waves at same cadence; drains own DMA

    if (it + 1 < 32) STAGE_TILE(bs ^ 1, kt0 + (it + 1) * 32)

    s16x8 kf[2][2], vf[4];
#pragma unroll
    for (int kb = 0; kb < 2; ++kb)
#pragma unroll
      for (int cc = 0; cc < 2; ++cc)
        kf[kb][cc] = *(const s16x8*)&KsW[bs * 2048 + kOff[kb][cc]];
#pragma unroll
    for (int cb = 0; cb < 4; ++cb)
      vf[cb] = *(const s16x8*)&VsW[bs * 2048 + vOff[cb]];

#pragma unroll
    for (int qb = 0; qb < 4; ++qb) {
      // S^T = K.Q^T : D[key][q]; lane q=c16, keys kb*16+quad*4+i
#pragma unroll
      for (int kb = 0; kb < 2; ++kb) {
        f32x4 s = (f32x4){-SHIFT, -SHIFT, -SHIFT, -SHIFT};
        s = mfma_bf16(kf[kb][0], qfb[qb][0], s);
        s = mfma_bf16(kf[kb][1], qfb[qb][1], s);
        uint2 pk;
        pk.x = pack_trunc(fast_exp2(s[0]), fast_exp2(s[1]));
        pk.y = pack_trunc(fast_exp2(s[2]), fast_exp2(s[3]));
        *(uint2*)&Pw[c16 * 40 + kb * 16 + quad * 4] = pk;
      }
      // PV: A = P[q][key] (contiguous b128), B = V^T[c][key]
      const s16x8 pf = *(const s16x8*)&Pw[c16 * 40 + quad * 8];
#pragma unroll
      for (int cb = 0; cb < 4; ++cb)
        o[qb][cb] = mfma_bf16(pf, vf[cb], o[qb][cb]);
      osum[qb] = mfma_bf16(pf, onesf, osum[qb]);
    }
  }
#undef STAGE_TILE

  // ---- combine the two K-halves in-block (exact: fixed-shift softmax) ----
  float* X  = (float*)(smem + 8192);           // wave1's dead staging, 16KB
  float* Lx = (float*)(smem + 16384 + 640);    // wave1's dead P area

  if (w == 1) {
#pragma unroll
    for (int qb = 0; qb < 4; ++qb) {
#pragma unroll
      for (int cb = 0; cb < 4; ++cb)
#pragma unroll
        for (int i = 0; i < 4; ++i)
          X[(qb * 16 + quad * 4 + i) * 64 + cb * 16 + c16] = o[qb][cb][i];
      if (c16 == 0)
#pragma unroll
        for (int i = 0; i < 4; ++i)
          Lx[qb * 16 + quad * 4 + i] = osum[qb][i];
    }
  }
  __syncthreads();
  if (w == 0) {
    const int b = bh >> 3, h = bh & 7;
#pragma unroll
    for (int qb = 0; qb < 4; ++qb) {
#pragma unroll
      for (int i = 0; i < 4; ++i) {
        const float l0 = __shfl(osum[qb][i], lane & 48);
        const int qq = qb * 16 + quad * 4 + i;
        const float inv = 1.0f / (l0 + Lx[qq]);
        const int q = q0 + qq;
        u16* dst = O + ((size_t)(b * SEQ + q)) * HC + h * CD;
#pragma unroll
        for (int cb = 0; cb < 4; ++cb)
          dst[cb * 16 + c16] =
              f2bf((o[qb][cb][i] + X[qq * 64 + cb * 16 + c16]) * inv);
      }
    }
  }
}

// ---------------------------------------------------------------------------
// Kernel 3: proj via MFMA. O bf16 [8192x512] @ WpT bf16 -> out f32 [8192x64].
// Wp B-frags preloaded to registers; O tile staged coalesced into LDS.
// Block 256 = 4 waves, k-split 4 + LDS f32 reduce. grid 512.
// ---------------------------------------------------------------------------
__global__ void __launch_bounds__(256) proj_kernel(
    const u16* __restrict__ O, const u16* __restrict__ WpT,
    const float* __restrict__ bias, float* __restrict__ out) {
  __shared__ __align__(16) u16 Ls[16 * 520];       // [row][k] stride 520
  __shared__ __align__(16) float Cred[4][64][20];  // [wave][col][row+pad]
  const int t = threadIdx.x;
  const int w = t >> 6, lane = t & 63, quad = lane >> 4, c16 = lane & 15;
  const int r0 = blockIdx.x * 16;

  // preload Wp B-frags to registers
  s16x8 wf[4][4];
#pragma unroll
  for (int kc = 0; kc < 4; ++kc)
#pragma unroll
    for (int nb = 0; nb < 4; ++nb)
      wf[kc][nb] = *(const s16x8*)(WpT + (size_t)(nb * 16 + c16) * HC +
                                   w * 128 + kc * 32 + quad * 8);

  // stage O tile coalesced: 16 lanes cover 256B of a row, 16 rows, 4 passes
  {
    const int row = t >> 4, cg = (t & 15) * 8;
#pragma unroll
    for (int p = 0; p < 4; ++p)
      *(int4*)&Ls[row * 520 + p * 128 + cg] =
          *(const int4*)(O + (size_t)(r0 + row) * HC + p * 128 + cg);
  }
  __syncthreads();

  f32x4 acc[4];
#pragma unroll
  for (int nb = 0; nb < 4; ++nb) acc[nb] = (f32x4){0.f, 0.f, 0.f, 0.f};
#pragma unroll
  for (int kc = 0; kc < 4; ++kc) {
    const s16x8 af =
        *(const s16x8*)&Ls[c16 * 520 + w * 128 + kc * 32 + quad * 8];
#pragma unroll
    for (int nb = 0; nb < 4; ++nb)
      acc[nb] = mfma_bf16(af, wf[kc][nb], acc[nb]);
  }

#pragma unroll
  for (int nb = 0; nb < 4; ++nb)
    *(f32x4*)&Cred[w][nb * 16 + c16][quad * 4] = acc[nb];
  __syncthreads();

  const int col = t & 63, rbase = (t >> 6) * 4;
  const float bv = bias[col];
#pragma unroll
  for (int j = 0; j < 4; ++j) {
    const int r = rbase + j;
    out[(size_t)(r0 + r) * CD + col] = Cred[0][col][r] + Cred[1][col][r] +
                                       Cred[2][col][r] + Cred[3][col][r] + bv;
  }
}

// ---------------------------------------------------------------------------
extern "C" void kernel_launch(void* const* d_in, const int* in_sizes, int n_in,
                              void* d_out, int out_size, void* d_ws, size_t ws_size,
                              hipStream_t stream) {
  (void)in_sizes; (void)n_in; (void)out_size; (void)ws_size;
  const float* x     = (const float*)d_in[0];
  const float* Wqkv  = (const float*)d_in[1];
  const float* Wproj = (const float*)d_in[2];
  const float* bproj = (const float*)d_in[3];
  float* out = (float*)d_out;

  // workspace layout (u16 units), 33.8 MB total (proven size)
  u16* WT  = (u16*)d_ws;                      // 1536*64
  u16* WpT = WT + 1536 * CD;                  // 64*512
  u16* Qw  = WpT + CD * HC;                   // 8 MB each below
  u16* Kw  = Qw + (size_t)BHN * SEQ * CD;
  u16* Vtw = Kw + (size_t)BHN * SEQ * CD;     // tiled-transposed V
  u16* Ow  = Vtw + (size_t)BHN * SEQ * CD;    // O bf16 [B,N,HC]

  prep_kernel<<<384, 256, 0, stream>>>(Wqkv, Wproj, WT, WpT);
  qkv_kernel<<<dim3(128, 8), 256, 0, stream>>>(x, WT, Qw, Kw, Vtw);
  attn_kernel<<<dim3(32, 32), 128, 0, stream>>>(Qw, Kw, Vtw, Ow);
  proj_kernel<<<512, 256, 0, stream>>>(Ow, WpT, bproj, out);
}

// Round 9
// 123.136 us; speedup vs baseline: 1.7296x; 1.0237x over previous
//
#include <hip/hip_runtime.h>

// Problem constants
#define NB 4
#define SEQ 2048
#define CD 64            // head dim == model dim
#define NHEAD 8
#define BHN (NB * NHEAD) // 32
#define ROWS (NB * SEQ)  // 8192
#define HC 512           // H*CD

#define QSCALE 0.18033688011112042f   // 0.125 * log2(e)
#define SHIFT  23.083120654223414f    // 16 * log2(e)

typedef float f32x4 __attribute__((ext_vector_type(4)));
typedef short s16x8 __attribute__((ext_vector_type(8)));
typedef unsigned short u16;
typedef unsigned int u32;

__device__ __forceinline__ u16 f2bf(float x) {
  union { float f; unsigned u; } v; v.f = x;
  unsigned r = v.u + 0x7FFFu + ((v.u >> 16) & 1u);
  return (u16)(r >> 16);
}

__device__ __forceinline__ float fast_exp2(float x) {
#if __has_builtin(__builtin_amdgcn_exp2f)
  return __builtin_amdgcn_exp2f(x);
#else
  return exp2f(x);
#endif
}

__device__ __forceinline__ u32 bitsf(float x) {
  union { float f; u32 u; } v; v.f = x; return v.u;
}

// pack hi16 of two f32 (truncating bf16 convert): {lo:=a_hi16, hi:=b_hi16}
__device__ __forceinline__ u32 pack_trunc(float a, float b) {
#if __has_builtin(__builtin_amdgcn_perm)
  return __builtin_amdgcn_perm(bitsf(b), bitsf(a), 0x07060302u);
#else
  return (bitsf(a) >> 16) | (bitsf(b) & 0xFFFF0000u);
#endif
}

__device__ __forceinline__ u32 pack_rne(float a, float b) {
  return (u32)f2bf(a) | ((u32)f2bf(b) << 16);
}

__device__ __forceinline__ f32x4 mfma_bf16(s16x8 a, s16x8 b, f32x4 c) {
  return __builtin_amdgcn_mfma_f32_16x16x32_bf16(a, b, c, 0, 0, 0);
}

// async global -> LDS DMA, 16B per lane; LDS dest = uniform base + lane*16
typedef __attribute__((address_space(1))) const u32* gp1;
typedef __attribute__((address_space(3))) u32* lp3;
__device__ __forceinline__ void dma16(const void* g, void* l) {
  __builtin_amdgcn_global_load_lds((gp1)g, (lp3)l, 16, 0, 0);
}

// ---------------------------------------------------------------------------
// Kernel 0: weight prep.
//   WT[n][k] = bf16(Wqkv[k][n])  (1536 x 64)
//   WpF: Wproj packed as MFMA B-fragments: frag f = kcg*4+nb (64 frags),
//        WpF[f*512 + lane*8 + j] = Wproj[(kcg*32+(lane>>4)*8+j)*64 + nb*16+(lane&15)]
// ---------------------------------------------------------------------------
__global__ void __launch_bounds__(256) prep_kernel(
    const float* __restrict__ Wqkv, const float* __restrict__ Wproj,
    u16* __restrict__ WT, u16* __restrict__ WpF) {
  const int idx = blockIdx.x * 256 + threadIdx.x;
  if (idx < 64 * 1536) {
    const int k = idx / 1536, n = idx % 1536;   // coalesced read
    WT[n * CD + k] = f2bf(Wqkv[idx]);
  }
  if (idx < 64 * 512) {
    const int f = idx >> 9;            // frag id 0..63
    const int lane = (idx >> 3) & 63;
    const int j = idx & 7;
    const int kcg = f >> 2, nb = f & 3;
    const int col = nb * 16 + (lane & 15);
    const int k = kcg * 32 + (lane >> 4) * 8 + j;
    WpF[idx] = f2bf(Wproj[k * 64 + col]);
  }
}

// ---------------------------------------------------------------------------
// Kernel 1: qkv via MFMA, LDS-staged. Q (scaled) & K as [B,H,N,64] bf16 with
// OPERAND-SWAPPED MFMA (C[col][row]: lane holds 4 consecutive cols of one
// row -> single 8B store per nb). V tiled-transposed Vt[bh][n>>5][c][n&31]
// (unswapped: lane packs 4 consecutive n). grid (128, 8), block 256.
// ---------------------------------------------------------------------------
__global__ void __launch_bounds__(256) qkv_kernel(
    const float* __restrict__ x, const u16* __restrict__ WT,
    u16* __restrict__ Q, u16* __restrict__ K, u16* __restrict__ Vt) {
  __shared__ __align__(16) u16 xs[64 * 72];    // [row][c] stride 72
  __shared__ __align__(16) u16 wts[192 * 72];  // [n][k]  stride 72

  const int t = threadIdx.x;
  const int w = t >> 6, lane = t & 63, quad = lane >> 4, c16 = lane & 15;
  const int rb = blockIdx.x * 64;
  const int c0 = blockIdx.y * 192;

  // stage x tile (64 rows x 64 c), f32 -> bf16, coalesced
  {
    const int row = t >> 2, cc0 = (t & 3) * 16;
    const float* xp = x + (size_t)(rb + row) * CD + cc0;
    union { u16 u[16]; int4 v[2]; } bx;
#pragma unroll
    for (int j = 0; j < 16; j += 4) {
      float4 xv = *(const float4*)(xp + j);
      bx.u[j] = f2bf(xv.x); bx.u[j + 1] = f2bf(xv.y);
      bx.u[j + 2] = f2bf(xv.z); bx.u[j + 3] = f2bf(xv.w);
    }
    *(int4*)&xs[row * 72 + cc0] = bx.v[0];
    *(int4*)&xs[row * 72 + cc0 + 8] = bx.v[1];
  }
  // stage WT tile (192 rows x 64 k), coalesced
#pragma unroll
  for (int pass = 0; pass < 3; ++pass) {
    const int row = pass * 64 + (t >> 2), cc0 = (t & 3) * 16;
    const u16* src = WT + (size_t)(c0 + row) * CD + cc0;
    *(int4*)&wts[row * 72 + cc0] = *(const int4*)src;
    *(int4*)&wts[row * 72 + cc0 + 8] = *(const int4*)(src + 8);
  }
  __syncthreads();

  s16x8 af[2];
#pragma unroll
  for (int kc = 0; kc < 2; ++kc)
    af[kc] = *(const s16x8*)&xs[(w * 16 + c16) * 72 + kc * 32 + quad * 8];

  const int rw = rb + w * 16;
  const int b = rw >> 11;
  const int nn0 = rw & (SEQ - 1);

#pragma unroll
  for (int nb = 0; nb < 12; ++nb) {
    const int cb = c0 + nb * 16;           // wave-uniform column base
    const int three = cb >> 9;
    const int h = (cb >> 6) & 7;
    const int ccb = cb & 63;
    const int bhv = b * NHEAD + h;
    s16x8 bf_[2];
#pragma unroll
    for (int kc = 0; kc < 2; ++kc)
      bf_[kc] = *(const s16x8*)&wts[(nb * 16 + c16) * 72 + kc * 32 + quad * 8];

    if (three == 2) {
      // V: C[row][col], lane col=c16 fixed, 4 consecutive n packed
      f32x4 acc = (f32x4){0.f, 0.f, 0.f, 0.f};
#pragma unroll
      for (int kc = 0; kc < 2; ++kc) acc = mfma_bf16(af[kc], bf_[kc], acc);
      uint2 pk;
      pk.x = pack_rne(acc[0], acc[1]);
      pk.y = pack_rne(acc[2], acc[3]);
      const size_t off = (size_t)bhv * (SEQ * CD) + (size_t)(nn0 >> 5) * 2048 +
                         (size_t)(ccb + c16) * 32 + (rw & 31) + quad * 4;
      *(uint2*)(Vt + off) = pk;
    } else {
      // Q/K: swapped operands -> C[col][row], lane row=c16, 4 cols packed
      f32x4 acc = (f32x4){0.f, 0.f, 0.f, 0.f};
#pragma unroll
      for (int kc = 0; kc < 2; ++kc) acc = mfma_bf16(bf_[kc], af[kc], acc);
      u16* dstp = (three == 0) ? Q : K;
      const float scl = (three == 0) ? QSCALE : 1.0f;
      uint2 pk;
      pk.x = pack_rne(acc[0] * scl, acc[1] * scl);
      pk.y = pack_rne(acc[2] * scl, acc[3] * scl);
      *(uint2*)(dstp + ((size_t)bhv * SEQ + nn0 + c16) * CD + ccb + quad * 4) =
          pk;
    }
  }
}

// ---------------------------------------------------------------------------
// Kernel 2: flash attention, IN-BLOCK K-SPLIT x2, BARRIER-FREE K-loop.
// Block = 2 waves; both waves same 64 q-rows, wave w keys [w*1024,(w+1)*1024).
// Staging is wave-private -> no s_barrier in loop: issue next tile's 8 DMAs,
// then s_waitcnt vmcnt(8) (in-order retire => previous tile landed). Waves
// free-run; combine (exact, fixed-shift softmax) via 2 barriers at the end.
// S^T = K.Q^T; P packed b64 (truncating v_perm), read back b128.
// grid (32, 32), 2048 waves = 8 waves/CU.
// ---------------------------------------------------------------------------
__global__ void __launch_bounds__(128, 2) attn_kernel(
    const u16* __restrict__ Q, const u16* __restrict__ K,
    const u16* __restrict__ Vt, u16* __restrict__ O) {
  // layout (u16): [w*8192]: K buf0|K buf1|V buf0|V buf1 (2048 each)
  //               [16384 + w*640]: per-wave P (16 rows x stride 40)
  __shared__ __align__(16) u16 smem[17664];

  const int t = threadIdx.x;
  const int w = t >> 6, lane = t & 63, quad = lane >> 4, c16 = lane & 15;
  const int bh = blockIdx.y;
  const int q0 = blockIdx.x * 64;
  const int kt0 = w * (SEQ / 2);

  u16* KsW = smem + w * 8192;          // [buf][2048]
  u16* VsW = smem + w * 8192 + 4096;   // [buf][2048]
  u16* Pw  = smem + 16384 + w * 640;   // [16*40]

  const u16* Qb = Q + (size_t)bh * SEQ * CD;
  const u16* Kb = K + (size_t)bh * SEQ * CD;
  const u16* Vb = Vt + (size_t)bh * SEQ * CD;  // tiled [n>>5][c][n&31]

  // Q B-operand fragments (same for both waves): B[k=c][n=q]
  s16x8 qfb[4][2];
#pragma unroll
  for (int qb = 0; qb < 4; ++qb)
#pragma unroll
    for (int cc = 0; cc < 2; ++cc)
      qfb[qb][cc] = *(const s16x8*)(Qb + (size_t)(q0 + qb * 16 + c16) * CD +
                                    cc * 32 + quad * 8);

  s16x8 onesf;
  {
    const short one = (c16 == 0) ? (short)0x3F80 : (short)0;
#pragma unroll
    for (int j = 0; j < 8; ++j) onesf[j] = one;
  }

  f32x4 o[4][4], osum[4];
#pragma unroll
  for (int qb = 0; qb < 4; ++qb) {
    osum[qb] = (f32x4){0.f, 0.f, 0.f, 0.f};
#pragma unroll
    for (int cb = 0; cb < 4; ++cb) o[qb][cb] = (f32x4){0.f, 0.f, 0.f, 0.f};
  }

  // staging lane constants (R5-verified XOR swizzle, 0 conflicts)
  const int krl = lane >> 3, kcl = (lane & 7) ^ ((lane >> 3) & 7);
  const int vrl = lane >> 2, vcl = (lane & 3) ^ ((lane >> 3) & 3);

  // fragment LDS offsets (swizzle-matched), relative to tile start
  int kOff[2][2], vOff[4];
#pragma unroll
  for (int kb = 0; kb < 2; ++kb)
#pragma unroll
    for (int cc = 0; cc < 2; ++cc)
      kOff[kb][cc] = (kb * 16 + c16) * 64 + (((cc * 4 + quad) ^ (c16 & 7)) * 8);
#pragma unroll
  for (int cb = 0; cb < 4; ++cb)
    vOff[cb] = (cb * 16 + c16) * 32 + ((quad ^ ((c16 >> 1) & 3)) * 8);

#define STAGE_TILE(buf_, kt_)                                                  \
  {                                                                            \
    const u16* ksrc = Kb + (size_t)(kt_) * CD;                                 \
    _Pragma("unroll") for (int d = 0; d < 4; ++d)                              \
        dma16(ksrc + (size_t)(d * 8 + krl) * CD + kcl * 8,                     \
              KsW + (buf_) * 2048 + d * 512);                                  \
    const u16* vsrc = Vb + (size_t)((kt_) >> 5) * 2048;                        \
    _Pragma("unroll") for (int d = 0; d < 4; ++d)                              \
        dma16(vsrc + (size_t)(d * 16 + vrl) * 32 + vcl * 8,                    \
              VsW + (buf_) * 2048 + d * 512);                                  \
  }

#define COMPUTE_TILE(bs_)                                                      \
  {                                                                            \
    s16x8 kf[2][2], vf[4];                                                     \
    _Pragma("unroll") for (int kb = 0; kb < 2; ++kb)                           \
        _Pragma("unroll") for (int cc = 0; cc < 2; ++cc)                       \
            kf[kb][cc] = *(const s16x8*)&KsW[(bs_) * 2048 + kOff[kb][cc]];     \
    _Pragma("unroll") for (int cb = 0; cb < 4; ++cb)                           \
        vf[cb] = *(const s16x8*)&VsW[(bs_) * 2048 + vOff[cb]];                 \
    _Pragma("unroll") for (int qb = 0; qb < 4; ++qb) {                         \
      _Pragma("unroll") for (int kb = 0; kb < 2; ++kb) {                       \
        f32x4 s = (f32x4){-SHIFT, -SHIFT, -SHIFT, -SHIFT};                     \
        s = mfma_bf16(kf[kb][0], qfb[qb][0], s);                               \
        s = mfma_bf16(kf[kb][1], qfb[qb][1], s);                               \
        uint2 pk;                                                              \
        pk.x = pack_trunc(fast_exp2(s[0]), fast_exp2(s[1]));                   \
        pk.y = pack_trunc(fast_exp2(s[2]), fast_exp2(s[3]));                   \
        *(uint2*)&Pw[c16 * 40 + kb * 16 + quad * 4] = pk;                      \
      }                                                                        \
      const s16x8 pf = *(const s16x8*)&Pw[c16 * 40 + quad * 8];                \
      _Pragma("unroll") for (int cb = 0; cb < 4; ++cb)                         \
          o[qb][cb] = mfma_bf16(pf, vf[cb], o[qb][cb]);                        \
      osum[qb] = mfma_bf16(pf, onesf, osum[qb]);                               \
    }                                                                          \
  }

  STAGE_TILE(0, kt0)

  for (int it = 0; it < 31; ++it) {
    const int bs = it & 1;
    STAGE_TILE(bs ^ 1, kt0 + (it + 1) * 32)
    __builtin_amdgcn_s_waitcnt(0x0F78);  // vmcnt(8): tile `it` landed
    COMPUTE_TILE(bs)
  }
  __builtin_amdgcn_s_waitcnt(0x0F70);    // vmcnt(0): last tile landed
  COMPUTE_TILE(1)
#undef STAGE_TILE
#undef COMPUTE_TILE

  // ---- combine the two K-halves in-block (exact: fixed-shift softmax) ----
  float* X  = (float*)(smem + 8192);           // wave1's dead staging, 16KB
  float* Lx = (float*)(smem + 16384 + 640);    // wave1's dead P area

  if (w == 1) {
#pragma unroll
    for (int qb = 0; qb < 4; ++qb) {
#pragma unroll
      for (int cb = 0; cb < 4; ++cb)
#pragma unroll
        for (int i = 0; i < 4; ++i)
          X[(qb * 16 + quad * 4 + i) * 64 + cb * 16 + c16] = o[qb][cb][i];
      if (c16 == 0)
#pragma unroll
        for (int i = 0; i < 4; ++i)
          Lx[qb * 16 + quad * 4 + i] = osum[qb][i];
    }
  }
  __syncthreads();
  if (w == 0) {
    const int b = bh >> 3, h = bh & 7;
#pragma unroll
    for (int qb = 0; qb < 4; ++qb) {
#pragma unroll
      for (int i = 0; i < 4; ++i) {
        const float l0 = __shfl(osum[qb][i], lane & 48);
        const int qq = qb * 16 + quad * 4 + i;
        const float inv = 1.0f / (l0 + Lx[qq]);
        const int q = q0 + qq;
        u16* dst = O + ((size_t)(b * SEQ + q)) * HC + h * CD;
#pragma unroll
        for (int cb = 0; cb < 4; ++cb)
          dst[cb * 16 + c16] =
              f2bf((o[qb][cb][i] + X[qq * 64 + cb * 16 + c16]) * inv);
      }
    }
  }
}

// ---------------------------------------------------------------------------
// Kernel 3: proj via MFMA. O bf16 [8192x512] @ WpF (fragment-packed bf16) ->
// out f32 [8192x64]. All global loads coalesced. Block 256 = 4 waves,
// k-split 4 + LDS f32 reduce. grid 512.
// ---------------------------------------------------------------------------
__global__ void __launch_bounds__(256) proj_kernel(
    const u16* __restrict__ O, const u16* __restrict__ WpF,
    const float* __restrict__ bias, float* __restrict__ out) {
  __shared__ __align__(16) u16 Ls[16 * 520];       // [row][k] stride 520
  __shared__ __align__(16) float Cred[4][64][20];  // [wave][col][row+pad]
  const int t = threadIdx.x;
  const int w = t >> 6, lane = t & 63, quad = lane >> 4, c16 = lane & 15;
  const int r0 = blockIdx.x * 16;

  // preload Wp B-frags (coalesced 1KB per load)
  s16x8 wf[4][4];
#pragma unroll
  for (int kc = 0; kc < 4; ++kc)
#pragma unroll
    for (int nb = 0; nb < 4; ++nb)
      wf[kc][nb] = *(const s16x8*)(WpF + ((((w * 4 + kc) * 4 + nb) << 9) +
                                          lane * 8));

  // stage O tile coalesced: 16 lanes cover 256B of a row, 16 rows, 4 passes
  {
    const int row = t >> 4, cg = (t & 15) * 8;
#pragma unroll
    for (int p = 0; p < 4; ++p)
      *(int4*)&Ls[row * 520 + p * 128 + cg] =
          *(const int4*)(O + (size_t)(r0 + row) * HC + p * 128 + cg);
  }
  __syncthreads();

  f32x4 acc[4];
#pragma unroll
  for (int nb = 0; nb < 4; ++nb) acc[nb] = (f32x4){0.f, 0.f, 0.f, 0.f};
#pragma unroll
  for (int kc = 0; kc < 4; ++kc) {
    const s16x8 af =
        *(const s16x8*)&Ls[c16 * 520 + w * 128 + kc * 32 + quad * 8];
#pragma unroll
    for (int nb = 0; nb < 4; ++nb)
      acc[nb] = mfma_bf16(af, wf[kc][nb], acc[nb]);
  }

#pragma unroll
  for (int nb = 0; nb < 4; ++nb)
    *(f32x4*)&Cred[w][nb * 16 + c16][quad * 4] = acc[nb];
  __syncthreads();

  const int col = t & 63, rbase = (t >> 6) * 4;
  const float bv = bias[col];
#pragma unroll
  for (int j = 0; j < 4; ++j) {
    const int r = rbase + j;
    out[(size_t)(r0 + r) * CD + col] = Cred[0][col][r] + Cred[1][col][r] +
                                       Cred[2][col][r] + Cred[3][col][r] + bv;
  }
}

// ---------------------------------------------------------------------------
extern "C" void kernel_launch(void* const* d_in, const int* in_sizes, int n_in,
                              void* d_out, int out_size, void* d_ws, size_t ws_size,
                              hipStream_t stream) {
  (void)in_sizes; (void)n_in; (void)out_size; (void)ws_size;
  const float* x     = (const float*)d_in[0];
  const float* Wqkv  = (const float*)d_in[1];
  const float* Wproj = (const float*)d_in[2];
  const float* bproj = (const float*)d_in[3];
  float* out = (float*)d_out;

  // workspace layout (u16 units), 33.8 MB total (proven size)
  u16* WT  = (u16*)d_ws;                      // 1536*64
  u16* WpF = WT + 1536 * CD;                  // 64*512 (fragment-packed)
  u16* Qw  = WpF + CD * HC;                   // 8 MB each below
  u16* Kw  = Qw + (size_t)BHN * SEQ * CD;
  u16* Vtw = Kw + (size_t)BHN * SEQ * CD;     // tiled-transposed V
  u16* Ow  = Vtw + (size_t)BHN * SEQ * CD;    // O bf16 [B,N,HC]

  prep_kernel<<<384, 256, 0, stream>>>(Wqkv, Wproj, WT, WpF);
  qkv_kernel<<<dim3(128, 8), 256, 0, stream>>>(x, WT, Qw, Kw, Vtw);
  attn_kernel<<<dim3(32, 32), 128, 0, stream>>>(Qw, Kw, Vtw, Ow);
  proj_kernel<<<512, 256, 0, stream>>>(Ow, WpF, bproj, out);
}